// Round 1
// baseline (709.638 us; speedup 1.0000x reference)
//
#include <hip/hip_runtime.h>

// Problem constants
#define NBANDS 64
#define LATENT 256
#define HIDDEN 512
#define GQ 8
#define KQ 1024
#define GD 32
#define NROWS 16000   // B*T = 16*1000

// d_out float offsets
#define OUT_BH   0              // 16*1000*64   = 1,024,000
#define OUT_ZE   1024000        // 16*1000*256  = 4,096,000
#define OUT_ZQ   5120000        // 16*1000*256  = 4,096,000
#define OUT_IDX  9216000        // 16*1000*8    =   128,000
#define OUT_LOSS 9344000        // 1

// ws float offsets
#define WS_H     0              // 16000*512 = 8,192,000 floats (reused for H1 then H2)
#define WS_CN    8192000        // 8*1024 = 8192 floats
#define WS_LOSS  8200192        // 1 float accumulator

// ---------------------------------------------------------------------------
// Tiled fp32 GEMM: C[M,N] = act(A[M,K] @ B[K,N] + bias[N])
// BM=BN=64, BK=16; block (16,16); 4x4 microtile per thread.
// M % 64 == 0, N % 64 == 0, K % 16 == 0 hold for all four layers.
// ---------------------------------------------------------------------------
template<bool RELU>
__global__ __launch_bounds__(256) void gemm_bias_act(
    const float* __restrict__ A, const float* __restrict__ B,
    const float* __restrict__ bias, float* __restrict__ C,
    int M, int N, int K) {
  __shared__ float As[16][64];   // [k][m]
  __shared__ float Bs[16][64];   // [k][n]

  const int tx = threadIdx.x;          // 0..15
  const int ty = threadIdx.y;          // 0..15
  const int tid = ty * 16 + tx;
  const int row0 = blockIdx.y * 64;
  const int col0 = blockIdx.x * 64;

  // A-load: thread -> (row, k-quad). 64 rows x 4 quads = 256 loads of float4.
  const int arow = tid >> 2;           // 0..63
  const int akq  = (tid & 3) << 2;     // 0,4,8,12
  // B-load: thread -> (k, col-quad). 16 k x 16 quads = 256 loads of float4.
  const int bkk  = tid >> 4;           // 0..15
  const int bcol = (tid & 15) << 2;    // 0..60

  float acc[4][4] = {};

  for (int k0 = 0; k0 < K; k0 += 16) {
    float4 av = *reinterpret_cast<const float4*>(
        &A[(size_t)(row0 + arow) * K + k0 + akq]);
    float4 bv = *reinterpret_cast<const float4*>(
        &B[(size_t)(k0 + bkk) * N + col0 + bcol]);
    __syncthreads();   // previous iteration's LDS reads complete
    As[akq + 0][arow] = av.x;
    As[akq + 1][arow] = av.y;
    As[akq + 2][arow] = av.z;
    As[akq + 3][arow] = av.w;
    *reinterpret_cast<float4*>(&Bs[bkk][bcol]) = bv;
    __syncthreads();

#pragma unroll
    for (int kk = 0; kk < 16; ++kk) {
      float4 a = *reinterpret_cast<const float4*>(&As[kk][ty * 4]);
      float4 b = *reinterpret_cast<const float4*>(&Bs[kk][tx * 4]);
      float ar[4] = {a.x, a.y, a.z, a.w};
      float br[4] = {b.x, b.y, b.z, b.w};
#pragma unroll
      for (int i = 0; i < 4; ++i)
#pragma unroll
        for (int j = 0; j < 4; ++j)
          acc[i][j] = fmaf(ar[i], br[j], acc[i][j]);
    }
  }

  // Epilogue: bias (+ReLU), vectorized store
  const float4 bb = *reinterpret_cast<const float4*>(&bias[col0 + tx * 4]);
  const float bias4[4] = {bb.x, bb.y, bb.z, bb.w};
#pragma unroll
  for (int i = 0; i < 4; ++i) {
    const int r = row0 + ty * 4 + i;
    float4 v;
    float* vp = &v.x;
#pragma unroll
    for (int j = 0; j < 4; ++j) {
      float t = acc[i][j] + bias4[j];
      if (RELU) t = fmaxf(t, 0.0f);
      vp[j] = t;
    }
    *reinterpret_cast<float4*>(&C[(size_t)r * N + col0 + tx * 4]) = v;
  }
}

// ---------------------------------------------------------------------------
// cn[g][k] = ||codebook[g][k]||^2 ; also zero the loss accumulator.
// ---------------------------------------------------------------------------
__global__ void cn_kernel(const float* __restrict__ cb, float* __restrict__ cn,
                          float* __restrict__ loss_acc) {
  const int i = blockIdx.x * 256 + threadIdx.x;
  if (i == 0) loss_acc[0] = 0.0f;
  if (i < GQ * KQ) {
    const float* c = cb + (size_t)i * GD;
    float s = 0.0f;
#pragma unroll
    for (int d = 0; d < GD; ++d) s = fmaf(c[d], c[d], s);
    cn[i] = s;
  }
}

// ---------------------------------------------------------------------------
// VQ: one thread per row, one group per block (g wave-uniform -> scalar
// codebook loads). argmin_k (cn[k] - 2*z.c_k); strict < keeps first min.
// Writes z_q, idx (as float), and block-reduced SSE via one atomicAdd.
// ---------------------------------------------------------------------------
__global__ __launch_bounds__(256) void vq_kernel(
    const float* __restrict__ z_e, const float* __restrict__ cb,
    const float* __restrict__ cn, float* __restrict__ z_q,
    float* __restrict__ idx_out, float* __restrict__ loss_acc) {
  const int g = blockIdx.y;
  const int n = blockIdx.x * 256 + threadIdx.x;
  const bool active = (n < NROWS);
  const int nn = active ? n : (NROWS - 1);

  // Load this thread's z (32 floats)
  float z[GD];
  const float4* zv = reinterpret_cast<const float4*>(
      &z_e[(size_t)nn * LATENT + g * GD]);
#pragma unroll
  for (int q = 0; q < 8; ++q) {
    float4 v = zv[q];
    z[q * 4 + 0] = v.x; z[q * 4 + 1] = v.y;
    z[q * 4 + 2] = v.z; z[q * 4 + 3] = v.w;
  }

  const float* cbg = cb + (size_t)g * KQ * GD;
  const float* cng = cn + (size_t)g * KQ;

  float best = 3.0e38f;
  int bidx = 0;
#pragma unroll 2
  for (int k = 0; k < KQ; ++k) {
    const float* c = cbg + k * GD;   // wave-uniform address -> s_load
    float dot = 0.0f;
#pragma unroll
    for (int d = 0; d < GD; ++d) dot = fmaf(c[d], z[d], dot);
    const float dist = fmaf(-2.0f, dot, cng[k]);
    if (dist < best) { best = dist; bidx = k; }
  }

  // Gather chosen codeword, compute SSE, write outputs
  const float* c = cbg + (size_t)bidx * GD;
  float sse = 0.0f;
  float cw[GD];
#pragma unroll
  for (int q = 0; q < 8; ++q) {
    float4 v = *reinterpret_cast<const float4*>(&c[q * 4]);
    cw[q * 4 + 0] = v.x; cw[q * 4 + 1] = v.y;
    cw[q * 4 + 2] = v.z; cw[q * 4 + 3] = v.w;
  }
#pragma unroll
  for (int d = 0; d < GD; ++d) {
    const float diff = cw[d] - z[d];
    sse = fmaf(diff, diff, sse);
  }
  if (active) {
    float4* zq = reinterpret_cast<float4*>(&z_q[(size_t)n * LATENT + g * GD]);
#pragma unroll
    for (int q = 0; q < 8; ++q)
      zq[q] = make_float4(cw[q * 4], cw[q * 4 + 1], cw[q * 4 + 2], cw[q * 4 + 3]);
    idx_out[(size_t)n * GQ + g] = (float)bidx;
  } else {
    sse = 0.0f;
  }

  // Block reduction of SSE, single atomic per block
  __shared__ float red[256];
  red[threadIdx.x] = sse;
  __syncthreads();
  for (int s = 128; s > 0; s >>= 1) {
    if (threadIdx.x < s) red[threadIdx.x] += red[threadIdx.x + s];
    __syncthreads();
  }
  if (threadIdx.x == 0) atomicAdd(loss_acc, red[0]);
}

// vq_loss = 0.25*(codebook_loss + commit_loss); both equal numerically
//         = 0.5 * total_sse / (NROWS * GD)
__global__ void loss_kernel(const float* __restrict__ acc,
                            float* __restrict__ out) {
  out[0] = 0.5f * acc[0] / (float)((size_t)NROWS * GD);
}

// ---------------------------------------------------------------------------
extern "C" void kernel_launch(void* const* d_in, const int* in_sizes, int n_in,
                              void* d_out, int out_size, void* d_ws, size_t ws_size,
                              hipStream_t stream) {
  const float* bands  = (const float*)d_in[0];
  const float* enc_w1 = (const float*)d_in[1];
  const float* enc_b1 = (const float*)d_in[2];
  const float* enc_w2 = (const float*)d_in[3];
  const float* enc_b2 = (const float*)d_in[4];
  const float* cbooks = (const float*)d_in[5];
  const float* dec_w1 = (const float*)d_in[6];
  const float* dec_b1 = (const float*)d_in[7];
  const float* dec_w2 = (const float*)d_in[8];
  const float* dec_b2 = (const float*)d_in[9];

  float* out = (float*)d_out;
  float* ws  = (float*)d_ws;

  float* bands_hat = out + OUT_BH;
  float* z_e       = out + OUT_ZE;
  float* z_q       = out + OUT_ZQ;
  float* idx_f     = out + OUT_IDX;
  float* loss_out  = out + OUT_LOSS;

  float* H        = ws + WS_H;     // 16000x512, reused for enc and dec hidden
  float* cn       = ws + WS_CN;
  float* loss_acc = ws + WS_LOSS;

  const dim3 blk(16, 16);

  // cn precompute (+ zero loss accumulator)
  cn_kernel<<<dim3((GQ * KQ + 255) / 256), dim3(256), 0, stream>>>(cbooks, cn, loss_acc);

  // Encoder: H = relu(bands @ enc_w1 + b1); z_e = H @ enc_w2 + b2
  gemm_bias_act<true ><<<dim3(HIDDEN / 64, NROWS / 64), blk, 0, stream>>>(
      bands, enc_w1, enc_b1, H, NROWS, HIDDEN, NBANDS);
  gemm_bias_act<false><<<dim3(LATENT / 64, NROWS / 64), blk, 0, stream>>>(
      H, enc_w2, enc_b2, z_e, NROWS, LATENT, HIDDEN);

  // VQ
  vq_kernel<<<dim3((NROWS + 255) / 256, GQ), dim3(256), 0, stream>>>(
      z_e, cbooks, cn, z_q, idx_f, loss_acc);

  // Decoder: H = relu(z_q @ dec_w1 + b1); bands_hat = H @ dec_w2 + b2
  gemm_bias_act<true ><<<dim3(HIDDEN / 64, NROWS / 64), blk, 0, stream>>>(
      z_q, dec_w1, dec_b1, H, NROWS, HIDDEN, LATENT);
  gemm_bias_act<false><<<dim3(NBANDS / 64, NROWS / 64), blk, 0, stream>>>(
      H, dec_w2, dec_b2, bands_hat, NROWS, NBANDS, HIDDEN);

  // Finalize scalar loss
  loss_kernel<<<1, 1, 0, stream>>>(loss_acc, loss_out);
}